// Round 10
// baseline (2732.844 us; speedup 1.0000x reference)
//
#include <hip/hip_runtime.h>

#define NB 2048
#define NT 1024

typedef _Float16 half2_t __attribute__((ext_vector_type(2)));
union F4H { float4 f; half2_t h[4]; };

__device__ __forceinline__ float tanh_fast(float x) {
    return fmaf(2.0f, __builtin_amdgcn_rcpf(1.0f + __builtin_amdgcn_exp2f(-2.8853900817779268f * x)), -1.0f);
}

__global__ void zero_loss_kernel(float* out) { out[0] = 0.0f; }

// Pack the three 128x32 matrices into an f16 blob: blob[R][0:32]=w_hh0[R],
// [32:64]=w_ih1[R], [64:96]=w_hh1[R]. 24576 B total -> L1-resident (32 KB/CU),
// shared by every wave on the CU. Runs every launch (d_ws is poisoned).
__global__ void prep_weights(const float* __restrict__ w_hh0,
                             const float* __restrict__ w_ih1,
                             const float* __restrict__ w_hh1,
                             _Float16* __restrict__ blob) {
    int i = blockIdx.x * blockDim.x + threadIdx.x;
    if (i < 128 * 32) {
        int R = i >> 5, k = i & 31;
        blob[R * 96 +      k] = (_Float16)w_hh0[i];
        blob[R * 96 + 32 + k] = (_Float16)w_ih1[i];
        blob[R * 96 + 64 + k] = (_Float16)w_hh1[i];
    }
}

#define FDOT(acc, w, hh) acc = __builtin_amdgcn_fdot2((w), (hh), (acc), false)
// 16 MACs from one 16B weight load x one 16B LDS fragment
#define DOT4W(a0, a1, W, U) \
  FDOT(a0, (W).h[0], (U).h[0]); FDOT(a1, (W).h[1], (U).h[1]); \
  FDOT(a0, (W).h[2], (U).h[2]); FDOT(a1, (W).h[3], (U).h[3]);

// Weights are NOT register-resident by design: 6 rounds proved the allocator
// parks large per-lane arrays in AGPRs (v_accvgpr_read per use). Instead each
// lane re-loads its 3 rows (192 B) per step from the L1-resident blob; a
// per-iteration pointer launder stops LICM from hoisting the loads back.
__global__ __launch_bounds__(128) __attribute__((amdgpu_waves_per_eu(4, 4)))
void decoder_lstm_kernel(const float* __restrict__ seq,    // (B,T,1)
                         const float* __restrict__ z,      // (B,32)
                         const float* __restrict__ w_ih0,  // (128,1)
                         const float* __restrict__ b_ih0,  // (128,)
                         const float* __restrict__ b_hh0,  // (128,)
                         const float* __restrict__ b_ih1,  // (128,)
                         const float* __restrict__ b_hh1,  // (128,)
                         const float* __restrict__ w_out,  // (1,32)
                         const float* __restrict__ b_out,  // (1,)
                         const _Float16* __restrict__ blob,// (128,96) f16
                         float* __restrict__ out)          // [0]=loss, [1..]=recovered
{
    const int tid = threadIdx.x;
    const int w   = tid >> 6;          // wave: units [16w, 16w+16)
    const int l   = tid & 63;
    const int q   = l >> 4;            // gate 0=i 1=f 2=g 3=o
    const int u   = 16 * w + (l & 15); // hidden unit
    const int R   = q * 32 + u;        // global gate row
    const int b   = blockIdx.x;

    __shared__ __align__(16) _Float16 h0buf[2][32];   // ping-pong h0
    __shared__ __align__(16) _Float16 h1buf[2][32];   // ping-pong h1
    __shared__ float pb[2];                            // per-wave pred partials

    const _Float16* wp = blob + R * 96;   // this lane's packed rows

    const float wih0R = w_ih0[R];
    const float bias0 = b_ih0[R] + b_hh0[R];
    const float bias1 = b_ih1[R] + b_hh1[R];

    // activation personality: gate 2 (g) is tanh, others sigmoid
    const float m2 = (q == 2) ? 1.0f : 0.0f;
    const float eM = (q == 2) ? -2.8853900817779268f : -1.4426950408889634f;

    const float wOutL = (l < 16) ? w_out[u] : 0.0f;   // 0 elsewhere -> clean reduce
    const float bOut  = b_out[0];

    const float cz = z[(size_t)b * 32 + u];
    float c0 = cz, c1 = cz;
    if (l < 16) { h0buf[0][u] = (_Float16)cz; h1buf[0][u] = (_Float16)cz; }
    float pred = 0.0f, sse = 0.0f, xreg = 0.0f;

    const float* seq_b = seq + (size_t)b * NT;
    float* out_b = out + 1 + (size_t)b * NT;

    __syncthreads();

    for (int t = 0; t < NT; ++t) {
        const int par = t & 1;

        // launder: loads below cannot be hoisted/CSE'd out of the loop
        const _Float16* wq = wp;
        asm("" : "+v"(wq));

        if (w == 0 && (t & 63) == 0) xreg = seq_b[t + l];   // coalesced per 64 steps

        // ---- cell 0 weights (w_hh0 row, 4x16B from L1) + h0 frags
        F4H Wa, Wb, Wc, Wd;
        Wa.f = *(const float4*)(wq +  0);
        Wb.f = *(const float4*)(wq +  8);
        Wc.f = *(const float4*)(wq + 16);
        Wd.f = *(const float4*)(wq + 24);

        F4H U0, U1, U2, U3;
        { const float4* p0 = (const float4*)h0buf[par];
          U0.f = p0[0]; U1.f = p0[1]; U2.f = p0[2]; U3.f = p0[3]; }

        // v = w_hh0[R].h0 + b0[R] + pred*w_ih0[R]
        float a0 = fmaf(pred, wih0R, bias0), a1 = 0.0f;
        DOT4W(a0, a1, Wa, U0); DOT4W(a0, a1, Wb, U1);
        DOT4W(a0, a1, Wc, U2); DOT4W(a0, a1, Wd, U3);
        float v  = a0 + a1;
        float s  = __builtin_amdgcn_rcpf(1.0f + __builtin_amdgcn_exp2f(eM * v));
        float av = fmaf(m2, s - 1.0f, s);           // sig(v) or tanh(v)

        // issue cell1's w_ih1 row loads now: latency hides under combine+barrier
        F4H Ia, Ib, Ic, Id;
        Ia.f = *(const float4*)(wq + 32);
        Ib.f = *(const float4*)(wq + 40);
        Ic.f = *(const float4*)(wq + 48);
        Id.f = *(const float4*)(wq + 56);

        // gate combine (valid on lanes l<16; bounded garbage elsewhere)
        float x16 = __shfl_xor(av, 16);   // sig(f)
        float x32 = __shfl_xor(av, 32);   // tanh(g)
        float x48 = __shfl_xor(av, 48);   // sig(o)
        c0 = fmaf(x16, c0, av * x32);
        float h0n = x48 * tanh_fast(c0);
        if (l < 16) h0buf[par ^ 1][u] = (_Float16)h0n;
        __syncthreads();                 // h0n exchange

        // ---- cell 1: w_hh1 row loads + fresh h0n / h1 frags
        F4H Ha, Hb, Hc, Hd;
        Ha.f = *(const float4*)(wq + 64);
        Hb.f = *(const float4*)(wq + 72);
        Hc.f = *(const float4*)(wq + 80);
        Hd.f = *(const float4*)(wq + 88);

        F4H V0, V1, V2, V3, X0, X1, X2, X3;
        { const float4* p  = (const float4*)h0buf[par ^ 1];
          const float4* p1 = (const float4*)h1buf[par];
          V0.f = p[0];  V1.f = p[1];  V2.f = p[2];  V3.f = p[3];
          X0.f = p1[0]; X1.f = p1[1]; X2.f = p1[2]; X3.f = p1[3]; }

        float d0 = bias1, d1 = 0.0f;
        DOT4W(d0, d1, Ia, V0); DOT4W(d0, d1, Ib, V1);
        DOT4W(d0, d1, Ic, V2); DOT4W(d0, d1, Id, V3);
        float d2 = 0.0f, d3 = 0.0f;
        DOT4W(d2, d3, Ha, X0); DOT4W(d2, d3, Hb, X1);
        DOT4W(d2, d3, Hc, X2); DOT4W(d2, d3, Hd, X3);
        float v1  = (d0 + d1) + (d2 + d3);
        float s1  = __builtin_amdgcn_rcpf(1.0f + __builtin_amdgcn_exp2f(eM * v1));
        float av1 = fmaf(m2, s1 - 1.0f, s1);

        float y16 = __shfl_xor(av1, 16);
        float y32 = __shfl_xor(av1, 32);
        float y48 = __shfl_xor(av1, 48);
        c1 = fmaf(y16, c1, av1 * y32);
        float h1n = y48 * tanh_fast(c1);
        if (l < 16) h1buf[par ^ 1][u] = (_Float16)h1n;

        // pred partial: nonzero only on lanes 0..15 (this wave's 16 units)
        float term = wOutL * h1n;
        term += __shfl_xor(term, 1);
        term += __shfl_xor(term, 2);
        term += __shfl_xor(term, 4);
        term += __shfl_xor(term, 8);
        if (l == 0) pb[w] = term;
        __syncthreads();                 // h1n + pred exchange

        pred = bOut + pb[0] + pb[1];

        if (w == 0) {
            out_b[t] = pred;                          // uniform: 1 transaction
            float d    = xreg - pred;
            float dsel = ((t & 63) == l) ? d : 0.0f;  // lane t&63 owns step t
            sse = fmaf(dsel, d, sse);
        }
    }

    // wave0 SSE reduction, one atomic per block; 1/(B*T) = 2^-21 exact
    if (w == 0) {
        sse += __shfl_xor(sse, 1);
        sse += __shfl_xor(sse, 2);
        sse += __shfl_xor(sse, 4);
        sse += __shfl_xor(sse, 8);
        sse += __shfl_xor(sse, 16);
        sse += __shfl_xor(sse, 32);
        if (l == 0) atomicAdd(out, sse * (1.0f / ((float)NB * (float)NT)));
    }
}

extern "C" void kernel_launch(void* const* d_in, const int* in_sizes, int n_in,
                              void* d_out, int out_size, void* d_ws, size_t ws_size,
                              hipStream_t stream) {
    const float* seq   = (const float*)d_in[0];
    const float* z     = (const float*)d_in[1];
    // d_in[2] = lengths (unused; reference ignores it)
    const float* w_ih0 = (const float*)d_in[3];
    const float* w_hh0 = (const float*)d_in[4];
    const float* b_ih0 = (const float*)d_in[5];
    const float* b_hh0 = (const float*)d_in[6];
    const float* w_ih1 = (const float*)d_in[7];
    const float* w_hh1 = (const float*)d_in[8];
    const float* b_ih1 = (const float*)d_in[9];
    const float* b_hh1 = (const float*)d_in[10];
    const float* w_out = (const float*)d_in[11];
    const float* b_out = (const float*)d_in[12];
    float* out = (float*)d_out;
    _Float16* blob = (_Float16*)d_ws;   // 24576 B used

    hipLaunchKernelGGL(zero_loss_kernel, dim3(1), dim3(1), 0, stream, out);
    hipLaunchKernelGGL(prep_weights, dim3(16), dim3(256), 0, stream,
                       w_hh0, w_ih1, w_hh1, blob);
    hipLaunchKernelGGL(decoder_lstm_kernel, dim3(NB), dim3(128), 0, stream,
                       seq, z, w_ih0, b_ih0, b_hh0, b_ih1, b_hh1,
                       w_out, b_out, blob, out);
}

// Round 11
// 1874.136 us; speedup vs baseline: 1.4582x; 1.4582x over previous
//
#include <hip/hip_runtime.h>

#define NB 2048
#define NT 1024

typedef _Float16 half2_t __attribute__((ext_vector_type(2)));
union F4H { float4 f; half2_t h[4]; };

__device__ __forceinline__ float tanh_fast(float x) {
    return fmaf(2.0f, __builtin_amdgcn_rcpf(1.0f + __builtin_amdgcn_exp2f(-2.8853900817779268f * x)), -1.0f);
}

__global__ void zero_loss_kernel(float* out) { out[0] = 0.0f; }

#define LD4(P, i) (*(const float4*)&(P)[i])
#define FDOT(acc, w, hh) acc = __builtin_amdgcn_fdot2((w), (hh), (acc), false)

// 4 f32 -> 2 half2
#define CVTQ(n0, n1, p, i) { float4 r_ = LD4(p, i); \
  n0.x=(_Float16)r_.x; n0.y=(_Float16)r_.y; n1.x=(_Float16)r_.z; n1.y=(_Float16)r_.w; }

// HALF a weight row (16 wide) as 8 named half2 = 8 VGPRs
#define DECL_HALFROW(n, src, row, kb) \
  half2_t n##0,n##1,n##2,n##3,n##4,n##5,n##6,n##7; \
  CVTQ(n##0, n##1, src, (row)*32 + (kb) + 0)  CVTQ(n##2, n##3, src, (row)*32 + (kb) + 4) \
  CVTQ(n##4, n##5, src, (row)*32 + (kb) + 8)  CVTQ(n##6, n##7, src, (row)*32 + (kb) + 12)

// 16 MACs: 8 fdot2 against two 16B LDS fragments
#define DOT8(a0, a1, n, U0, U1) \
  FDOT(a0, n##0, (U0).h[0]); FDOT(a1, n##1, (U0).h[1]); \
  FDOT(a0, n##2, (U0).h[2]); FDOT(a1, n##3, (U0).h[3]); \
  FDOT(a0, n##4, (U1).h[0]); FDOT(a1, n##5, (U1).h[1]); \
  FDOT(a0, n##6, (U1).h[2]); FDOT(a1, n##7, (U1).h[3]);

// Block = 4 waves = one sequence. Lane (w, q=l>>4, h=(l>>3)&1, e=l&7) owns
// K-HALF h of gate row R = q*32 + 8w + e -> 24 half2 weight VGPRs. Total
// demand ~55 < 64 = the budget at even the max occupancy target, so the
// allocator has no reason to offload anything (6 rounds proved it offloads
// whenever demand exceeds budget). 2048x4 waves = 8 waves/SIMD = full TLP.
__global__ __launch_bounds__(256)
void decoder_lstm_kernel(const float* __restrict__ seq,    // (B,T,1)
                         const float* __restrict__ z,      // (B,32)
                         const float* __restrict__ w_ih0,  // (128,1)
                         const float* __restrict__ w_hh0,  // (128,32)
                         const float* __restrict__ b_ih0,  // (128,)
                         const float* __restrict__ b_hh0,  // (128,)
                         const float* __restrict__ w_ih1,  // (128,32)
                         const float* __restrict__ w_hh1,  // (128,32)
                         const float* __restrict__ b_ih1,  // (128,)
                         const float* __restrict__ b_hh1,  // (128,)
                         const float* __restrict__ w_out,  // (1,32)
                         const float* __restrict__ b_out,  // (1,)
                         float* __restrict__ out)          // [0]=loss, [1..]=recovered
{
    const int tid = threadIdx.x;
    const int w   = tid >> 6;          // wave 0..3: units [8w, 8w+8)
    const int l   = tid & 63;
    const int q   = l >> 4;            // gate 0=i 1=f 2=g 3=o
    const int h   = (l >> 3) & 1;      // k-half
    const int e   = l & 7;             // unit offset
    const int u   = 8 * w + e;         // hidden unit
    const int R   = q * 32 + u;        // global gate row
    const int kb  = 16 * h;            // k base (in elements)
    const int b   = blockIdx.x;

    __shared__ __align__(16) _Float16 h0buf[2][32];   // ping-pong h0
    __shared__ __align__(16) _Float16 h1buf[2][32];   // ping-pong h1
    __shared__ float pb[4];                            // per-wave pred partials

    // 24 half2 = 24 VGPRs of weights (half-rows of the three matrices)
    DECL_HALFROW(w0, w_hh0, R, kb)
    DECL_HALFROW(wi, w_ih1, R, kb)
    DECL_HALFROW(wh, w_hh1, R, kb)

    // bias/pred terms contributed only by the h=0 half (halves sum via xor8)
    const float bias0L = h ? 0.0f : (b_ih0[R] + b_hh0[R]);
    const float bias1L = h ? 0.0f : (b_ih1[R] + b_hh1[R]);
    const float wih0L  = h ? 0.0f : w_ih0[R];

    // activation personality: gate 2 (g) is tanh, others sigmoid
    const float m2 = (q == 2) ? 1.0f : 0.0f;
    const float eM = (q == 2) ? -2.8853900817779268f : -1.4426950408889634f;

    const float wOutL = (l < 8) ? w_out[u] : 0.0f;   // q=0,h=0 lanes only
    const float bOut  = b_out[0];

    // init: h0=c0=h1=c1=z, pred=0. c replicated across the 8 (q,h) lanes of u;
    // exact only on q=0 lanes (others drift bounded, tanh saturates, unused).
    const float cz = z[(size_t)b * 32 + u];
    float c0 = cz, c1 = cz;
    if (l < 8) { h0buf[0][u] = (_Float16)cz; h1buf[0][u] = (_Float16)cz; }
    float pred = 0.0f, sse = 0.0f, xreg = 0.0f;

    const float* seq_b = seq + (size_t)b * NT;
    float* out_b = out + 1 + (size_t)b * NT;

    __syncthreads();

    for (int t = 0; t < NT; ++t) {
        const int par = t & 1;
        if (w == 0 && (t & 63) == 0) xreg = seq_b[t + l];   // coalesced per 64 steps

        // this lane's k-half of h0 (32B): 2-address broadcast read -> conflict-free
        F4H U0, U1;
        U0.f = *(const float4*)&h0buf[par][kb];
        U1.f = *(const float4*)&h0buf[par][kb + 8];

        // ---- cell 0: v = w_hh0[R][kb:kb+16].h0half + (bias0 + pred*wih0)|h=0
        float a0 = fmaf(pred, wih0L, bias0L), a1 = 0.0f;
        DOT8(a0, a1, w0, U0, U1);
        float v = a0 + a1;
        v += __shfl_xor(v, 8);                       // combine k-halves
        float s  = __builtin_amdgcn_rcpf(1.0f + __builtin_amdgcn_exp2f(eM * v));
        float av = fmaf(m2, s - 1.0f, s);            // sig(v) or tanh(v)

        // gate combine (valid on q=0 lanes)
        float x16 = __shfl_xor(av, 16);   // sig(f)
        float x32 = __shfl_xor(av, 32);   // tanh(g)
        float x48 = __shfl_xor(av, 48);   // sig(o)
        c0 = fmaf(x16, c0, av * x32);
        float h0n = x48 * tanh_fast(c0);
        if (l < 8) h0buf[par ^ 1][u] = (_Float16)h0n;
        __syncthreads();                 // h0n exchange

        // ---- cell 1: v1 = w_ih1[R].h0n + w_hh1[R].h1 + b1 (k-split halves)
        F4H V0, V1, X0, X1;
        V0.f = *(const float4*)&h0buf[par ^ 1][kb];
        V1.f = *(const float4*)&h0buf[par ^ 1][kb + 8];
        X0.f = *(const float4*)&h1buf[par][kb];
        X1.f = *(const float4*)&h1buf[par][kb + 8];

        float d0 = bias1L, d1 = 0.0f;
        DOT8(d0, d1, wi, V0, V1);
        DOT8(d0, d1, wh, X0, X1);
        float v1 = d0 + d1;
        v1 += __shfl_xor(v1, 8);
        float s1  = __builtin_amdgcn_rcpf(1.0f + __builtin_amdgcn_exp2f(eM * v1));
        float av1 = fmaf(m2, s1 - 1.0f, s1);

        float y16 = __shfl_xor(av1, 16);
        float y32 = __shfl_xor(av1, 32);
        float y48 = __shfl_xor(av1, 48);
        c1 = fmaf(y16, c1, av1 * y32);
        float h1n = y48 * tanh_fast(c1);
        if (l < 8) h1buf[par ^ 1][u] = (_Float16)h1n;

        // pred partial: this wave's 8 units live on lanes l<8
        float term = wOutL * h1n;
        term += __shfl_xor(term, 1);
        term += __shfl_xor(term, 2);
        term += __shfl_xor(term, 4);
        if (l == 0) pb[w] = term;
        __syncthreads();                 // h1n + pred exchange

        pred = bOut + ((pb[0] + pb[1]) + (pb[2] + pb[3]));

        if (w == 0) {
            out_b[t] = pred;                          // uniform: 1 transaction
            float d    = xreg - pred;
            float dsel = ((t & 63) == l) ? d : 0.0f;  // lane t&63 owns step t
            sse = fmaf(dsel, d, sse);
        }
    }

    // wave0 SSE reduction, one atomic per block; 1/(B*T) = 2^-21 exact
    if (w == 0) {
        sse += __shfl_xor(sse, 1);
        sse += __shfl_xor(sse, 2);
        sse += __shfl_xor(sse, 4);
        sse += __shfl_xor(sse, 8);
        sse += __shfl_xor(sse, 16);
        sse += __shfl_xor(sse, 32);
        if (l == 0) atomicAdd(out, sse * (1.0f / ((float)NB * (float)NT)));
    }
}

extern "C" void kernel_launch(void* const* d_in, const int* in_sizes, int n_in,
                              void* d_out, int out_size, void* d_ws, size_t ws_size,
                              hipStream_t stream) {
    const float* seq   = (const float*)d_in[0];
    const float* z     = (const float*)d_in[1];
    // d_in[2] = lengths (unused; reference ignores it)
    const float* w_ih0 = (const float*)d_in[3];
    const float* w_hh0 = (const float*)d_in[4];
    const float* b_ih0 = (const float*)d_in[5];
    const float* b_hh0 = (const float*)d_in[6];
    const float* w_ih1 = (const float*)d_in[7];
    const float* w_hh1 = (const float*)d_in[8];
    const float* b_ih1 = (const float*)d_in[9];
    const float* b_hh1 = (const float*)d_in[10];
    const float* w_out = (const float*)d_in[11];
    const float* b_out = (const float*)d_in[12];
    float* out = (float*)d_out;

    hipLaunchKernelGGL(zero_loss_kernel, dim3(1), dim3(1), 0, stream, out);
    hipLaunchKernelGGL(decoder_lstm_kernel, dim3(NB), dim3(256), 0, stream,
                       seq, z, w_ih0, w_hh0, b_ih0, b_hh0,
                       w_ih1, w_hh1, b_ih1, b_hh1, w_out, b_out, out);
}

// Round 13
// 1146.651 us; speedup vs baseline: 2.3833x; 1.6344x over previous
//
#include <hip/hip_runtime.h>

#define NB 2048
#define NT 1024

typedef _Float16 half2_t __attribute__((ext_vector_type(2)));
typedef float    vf4     __attribute__((ext_vector_type(4)));   // primitive vector: volatile-loadable
union F4H { vf4 f; half2_t h[4]; };

__device__ __forceinline__ float tanh_fast(float x) {
    return fmaf(2.0f, __builtin_amdgcn_rcpf(1.0f + __builtin_amdgcn_exp2f(-2.8853900817779268f * x)), -1.0f);
}

__global__ void zero_loss_kernel(float* out) { out[0] = 0.0f; }

// Pack the three 128x32 f32 matrices into one f16 blob:
// blob[R*96 + 0:32]=w_hh0[R], +32:64=w_ih1[R], +64:96=w_hh1[R]. 24 KB.
// Pre-converted so the register-resident weights have NO cvt chain the
// compiler could rematerialize. Runs every launch (d_ws is poisoned).
__global__ void prep_weights(const float* __restrict__ w_hh0,
                             const float* __restrict__ w_ih1,
                             const float* __restrict__ w_hh1,
                             _Float16* __restrict__ blob) {
    int i = blockIdx.x * blockDim.x + threadIdx.x;
    if (i < 128 * 32) {
        int R = i >> 5, k = i & 31;
        blob[R * 96 +      k] = (_Float16)w_hh0[i];
        blob[R * 96 + 32 + k] = (_Float16)w_ih1[i];
        blob[R * 96 + 64 + k] = (_Float16)w_hh1[i];
    }
}

#define FDOT(acc, w, hh) acc = __builtin_amdgcn_fdot2((w), (hh), (acc), false)
// 16 MACs: one 16B weight fragment x one 16B h fragment
#define DOT4W(a0, a1, W, U) \
  FDOT(a0, (W).h[0], (U).h[0]); FDOT(a1, (W).h[1], (U).h[1]); \
  FDOT(a0, (W).h[2], (U).h[2]); FDOT(a1, (W).h[3], (U).h[3]);

// Block = 2 waves = one sequence; lane (w, q=l>>4) owns gate row R=q*32+u,
// u=16w+(l&15). Weights: 12 x VOLATILE vf4 loads of the f16 blob = 48 VGPRs
// whose value chain CANNOT be re-sourced (volatile loads may not be
// re-executed) -> the L1-reload pathology of R7-R11 is illegal here. Demand
// ~90 fits the 128-VGPR budget from waves_per_eu(4,4); grid = 4096 waves =
// exactly 4/SIMD, so the cap costs nothing.
__global__ __launch_bounds__(128) __attribute__((amdgpu_waves_per_eu(4, 4)))
void decoder_lstm_kernel(const float* __restrict__ seq,    // (B,T,1)
                         const float* __restrict__ z,      // (B,32)
                         const float* __restrict__ w_ih0,  // (128,1)
                         const float* __restrict__ b_ih0,  // (128,)
                         const float* __restrict__ b_hh0,  // (128,)
                         const float* __restrict__ b_ih1,  // (128,)
                         const float* __restrict__ b_hh1,  // (128,)
                         const float* __restrict__ w_out,  // (1,32)
                         const float* __restrict__ b_out,  // (1,)
                         const _Float16* __restrict__ blob,// (128,96) f16
                         float* __restrict__ out)          // [0]=loss, [1..]=recovered
{
    const int tid = threadIdx.x;
    const int w   = tid >> 6;          // wave: units [16w, 16w+16)
    const int l   = tid & 63;
    const int q   = l >> 4;            // gate 0=i 1=f 2=g 3=o
    const int u   = 16 * w + (l & 15); // hidden unit
    const int R   = q * 32 + u;        // global gate row
    const int b   = blockIdx.x;

    __shared__ __align__(16) _Float16 h0buf[2][32];   // ping-pong h0
    __shared__ __align__(16) _Float16 h1buf[2][32];   // ping-pong h1
    __shared__ float pb[2];                            // per-wave pred partials

    // ---- volatile weight loads: the 48 loaded regs must be carried ----
    const volatile vf4* wv = (const volatile vf4*)(blob + R * 96);
    F4H Wa, Wb, Wc, Wd,  Ia, Ib, Ic, Id,  Ha, Hb, Hc, Hd;
    Wa.f = wv[0];  Wb.f = wv[1];  Wc.f = wv[2];  Wd.f = wv[3];   // w_hh0 row
    Ia.f = wv[4];  Ib.f = wv[5];  Ic.f = wv[6];  Id.f = wv[7];   // w_ih1 row
    Ha.f = wv[8];  Hb.f = wv[9];  Hc.f = wv[10]; Hd.f = wv[11];  // w_hh1 row

    const float wih0R = w_ih0[R];
    const float bias0 = b_ih0[R] + b_hh0[R];
    const float bias1 = b_ih1[R] + b_hh1[R];

    // activation personality: gate 2 (g) is tanh, others sigmoid
    const float m2 = (q == 2) ? 1.0f : 0.0f;
    const float eM = (q == 2) ? -2.8853900817779268f : -1.4426950408889634f;

    const float wOutL = (l < 16) ? w_out[u] : 0.0f;   // 0 elsewhere -> clean reduce
    const float bOut  = b_out[0];

    const float cz = z[(size_t)b * 32 + u];
    float c0 = cz, c1 = cz;
    if (l < 16) { h0buf[0][u] = (_Float16)cz; h1buf[0][u] = (_Float16)cz; }
    float pred = 0.0f, sse = 0.0f, xreg = 0.0f;

    const float* seq_b = seq + (size_t)b * NT;
    float* out_b = out + 1 + (size_t)b * NT;

    __syncthreads();

    for (int t = 0; t < NT; ++t) {
        const int par = t & 1;
        if (w == 0 && (t & 63) == 0) xreg = seq_b[t + l];   // coalesced per 64 steps

        // broadcast frag reads for cell 0 (uniform address -> conflict-free)
        F4H U0, U1, U2, U3;
        { const vf4* p0 = (const vf4*)h0buf[par];
          U0.f = p0[0]; U1.f = p0[1]; U2.f = p0[2]; U3.f = p0[3]; }

        // ---- cell 0: v = w_hh0[R].h0 + b0[R] + pred*w_ih0[R]
        float a0 = fmaf(pred, wih0R, bias0), a1 = 0.0f;
        DOT4W(a0, a1, Wa, U0); DOT4W(a0, a1, Wb, U1);
        DOT4W(a0, a1, Wc, U2); DOT4W(a0, a1, Wd, U3);
        float v  = a0 + a1;
        float s  = __builtin_amdgcn_rcpf(1.0f + __builtin_amdgcn_exp2f(eM * v));
        float av = fmaf(m2, s - 1.0f, s);           // sig(v) or tanh(v)

        // gate combine (valid on q=0 lanes; bounded garbage elsewhere)
        float x16 = __shfl_xor(av, 16);   // sig(f)
        float x32 = __shfl_xor(av, 32);   // tanh(g)
        float x48 = __shfl_xor(av, 48);   // sig(o)
        c0 = fmaf(x16, c0, av * x32);
        float h0n = x48 * tanh_fast(c0);
        if (l < 16) h0buf[par ^ 1][u] = (_Float16)h0n;
        __syncthreads();                 // h0n exchange

        // ---- cell 1: v1 = w_ih1[R].h0n + w_hh1[R].h1 + b1[R]
        F4H V0, V1, V2, V3, X0, X1, X2, X3;
        { const vf4* p  = (const vf4*)h0buf[par ^ 1];
          const vf4* p1 = (const vf4*)h1buf[par];
          V0.f = p[0];  V1.f = p[1];  V2.f = p[2];  V3.f = p[3];
          X0.f = p1[0]; X1.f = p1[1]; X2.f = p1[2]; X3.f = p1[3]; }

        float d0 = bias1, d1 = 0.0f;
        DOT4W(d0, d1, Ia, V0); DOT4W(d0, d1, Ib, V1);
        DOT4W(d0, d1, Ic, V2); DOT4W(d0, d1, Id, V3);
        float d2 = 0.0f, d3 = 0.0f;
        DOT4W(d2, d3, Ha, X0); DOT4W(d2, d3, Hb, X1);
        DOT4W(d2, d3, Hc, X2); DOT4W(d2, d3, Hd, X3);
        float v1  = (d0 + d1) + (d2 + d3);
        float s1  = __builtin_amdgcn_rcpf(1.0f + __builtin_amdgcn_exp2f(eM * v1));
        float av1 = fmaf(m2, s1 - 1.0f, s1);

        float y16 = __shfl_xor(av1, 16);
        float y32 = __shfl_xor(av1, 32);
        float y48 = __shfl_xor(av1, 48);
        c1 = fmaf(y16, c1, av1 * y32);
        float h1n = y48 * tanh_fast(c1);
        if (l < 16) h1buf[par ^ 1][u] = (_Float16)h1n;

        // pred partial: nonzero only on lanes 0..15 (this wave's 16 units)
        float term = wOutL * h1n;
        term += __shfl_xor(term, 1);
        term += __shfl_xor(term, 2);
        term += __shfl_xor(term, 4);
        term += __shfl_xor(term, 8);
        if (l == 0) pb[w] = term;
        __syncthreads();                 // h1n + pred exchange

        pred = bOut + pb[0] + pb[1];

        if (w == 0) {
            out_b[t] = pred;                          // uniform: 1 transaction
            float d    = xreg - pred;
            float dsel = ((t & 63) == l) ? d : 0.0f;  // lane t&63 owns step t
            sse = fmaf(dsel, d, sse);
        }
    }

    // wave0 SSE reduction, one atomic per block; 1/(B*T) = 2^-21 exact
    if (w == 0) {
        sse += __shfl_xor(sse, 1);
        sse += __shfl_xor(sse, 2);
        sse += __shfl_xor(sse, 4);
        sse += __shfl_xor(sse, 8);
        sse += __shfl_xor(sse, 16);
        sse += __shfl_xor(sse, 32);
        if (l == 0) atomicAdd(out, sse * (1.0f / ((float)NB * (float)NT)));
    }
}

extern "C" void kernel_launch(void* const* d_in, const int* in_sizes, int n_in,
                              void* d_out, int out_size, void* d_ws, size_t ws_size,
                              hipStream_t stream) {
    const float* seq   = (const float*)d_in[0];
    const float* z     = (const float*)d_in[1];
    // d_in[2] = lengths (unused; reference ignores it)
    const float* w_ih0 = (const float*)d_in[3];
    const float* w_hh0 = (const float*)d_in[4];
    const float* b_ih0 = (const float*)d_in[5];
    const float* b_hh0 = (const float*)d_in[6];
    const float* w_ih1 = (const float*)d_in[7];
    const float* w_hh1 = (const float*)d_in[8];
    const float* b_ih1 = (const float*)d_in[9];
    const float* b_hh1 = (const float*)d_in[10];
    const float* w_out = (const float*)d_in[11];
    const float* b_out = (const float*)d_in[12];
    float* out = (float*)d_out;
    _Float16* blob = (_Float16*)d_ws;   // 24576 B used

    hipLaunchKernelGGL(zero_loss_kernel, dim3(1), dim3(1), 0, stream, out);
    hipLaunchKernelGGL(prep_weights, dim3(16), dim3(256), 0, stream,
                       w_hh0, w_ih1, w_hh1, blob);
    hipLaunchKernelGGL(decoder_lstm_kernel, dim3(NB), dim3(128), 0, stream,
                       seq, z, w_ih0, b_ih0, b_hh0, b_ih1, b_hh1,
                       w_out, b_out, blob, out);
}